// Round 11
// baseline (551.265 us; speedup 1.0000x reference)
//
#include <hip/hip_runtime.h>

// MaskedLoss: mean((roi*pred - roi*true)^2), roi = expanded bbox of mask fg.
// Shapes fixed: [4,1,160,160,160] fp32/fp32/int32.
//
// R11: 3 dispatches (init -> bbox -> loss), 16B/thread/iter (ONLY proven-good
// shape; 32B pairs were toxic in R8/R9), upfront register-staged loads to
// force per-thread MLP (R1-R10 showed VGPR 20-24 => ~2 loads in flight, and
// 2.7 TB/s cap invariant to occupancy/VALU/geometry -- MLP is the last
// untested axis).
//
// Layout: 1,024,000 quads/batch; 6400 quads per d-slice, 40 per (d,h) row.
// STRIDE = 1000 blocks * 256 thr = 256,000 quads = EXACTLY 40 d-slices ->
// (h,w) loop-invariant, d advances by 40/iter. ITERS=4.

namespace {
constexpr int BATCH = 4;
constexpr int DSZ = 160, HSZ = 160, WSZ = 160;
constexpr int SPATIAL = DSZ * HSZ * WSZ;      // 4,096,000
constexpr int QPB = SPATIAL / 4;              // 1,024,000
constexpr int NT = 256;
constexpr int PB = 1000;                      // blocks per batch
constexpr int STRIDE_Q = PB * NT;             // 256,000 quads = 40 d-slices
constexpr int ITERS = QPB / STRIDE_Q;         // 4
constexpr int DSTEP = 40;
constexpr int NPART = BATCH * PB;             // 4000
constexpr int TOTAL_BLOCKS = BATCH * PB;      // 4000 (per kernel)
constexpr int SENT_MIN = 1 << 30;

// ws layout (byte offsets); d_ws is poisoned 0xAA before every launch, so
// everything used must be re-initialized by ml_init each call.
constexpr int WS_NEG  = 0;     // int[12]: per-batch max(len-1 - min) per axis
constexpr int WS_MAX  = 64;    // int[12]: per-batch max per axis
constexpr int WS_CNTA = 128;   // int: bbox-kernel block counter
constexpr int WS_CNTB = 132;   // int: loss-kernel block counter
constexpr int WS_BOXP = 192;   // int[4][8]: lo/hi per axis per batch
constexpr int WS_PART = 384;   // float[NPART]
}

typedef int   vint4   __attribute__((ext_vector_type(4)));
typedef float vfloat4 __attribute__((ext_vector_type(4)));

__device__ __forceinline__ int wred_min(int v) {
#pragma unroll
  for (int o = 32; o; o >>= 1) v = min(v, __shfl_xor(v, o));
  return v;
}
__device__ __forceinline__ int wred_max(int v) {
#pragma unroll
  for (int o = 32; o; o >>= 1) v = max(v, __shfl_xor(v, o));
  return v;
}

// ---------------- init ----------------
__global__ void ml_init(int* __restrict__ ws_i) {
  if (threadIdx.x == 0) {
#pragma unroll
    for (int k = 0; k < 12; ++k) ws_i[k] = -1;        // WS_NEG
#pragma unroll
    for (int k = 0; k < 12; ++k) ws_i[16 + k] = -1;   // WS_MAX
    ws_i[32] = 0;                                     // WS_CNTA
    ws_i[33] = 0;                                     // WS_CNTB
  }
}

// replicate reference fp32 arithmetic exactly
__device__ __forceinline__ void axis_box(int mni, int mxi, int sh, int* lo_i, int* hi_i) {
  float mn = (float)mni, mx = (float)mxi;
  float c = (mx + mn) * 0.5f;
  float e = (mx - mn + 1.0f) * 0.5f * 1.2f;          // EXPAND = 1.2f
  float lo = fmaxf(0.0f, floorf(c - e));
  float hi = fminf((float)(sh - 1), floorf(c + e));  // hi EXCLUSIVE
  *lo_i = (int)lo;
  *hi_i = (int)hi;
}

// ---------------- bbox: scan mask, atomic reduce, last block -> box params ----------------
__global__ __launch_bounds__(NT) void ml_bbox(const int* __restrict__ mask,
                                              int* __restrict__ bneg,
                                              int* __restrict__ bmax,
                                              int* __restrict__ cntA,
                                              int* __restrict__ boxp) {
  const int b = blockIdx.y;
  const vint4* m4 = reinterpret_cast<const vint4*>(mask + (size_t)b * SPATIAL);

  const unsigned q0 = blockIdx.x * NT + threadIdx.x;   // < 256000
  const unsigned d0 = q0 / 6400u;
  const unsigned rem = q0 - d0 * 6400u;                // loop-invariant
  const unsigned h = rem / 40u;
  const int wb = (int)(rem - h * 40u) * 4;

  // stage all loads first: force 4 loads in flight per thread
  vint4 v[ITERS];
#pragma unroll
  for (int i = 0; i < ITERS; ++i) v[i] = m4[q0 + (size_t)i * STRIDE_Q];

  unsigned itermask = 0;  // bit i: any fg at d = d0 + 40*i
  int elemmask = 0;       // bit j: any fg at w = wb + j
#pragma unroll
  for (int i = 0; i < ITERS; ++i) {
    int e = (int)(v[i][0] > 0) | ((int)(v[i][1] > 0) << 1) |
            ((int)(v[i][2] > 0) << 2) | ((int)(v[i][3] > 0) << 3);
    elemmask |= e;
    itermask |= (e ? (1u << i) : 0u);
  }

  int dmin = SENT_MIN, dmax = -1, hmin = SENT_MIN, hmax = -1, wmin = SENT_MIN, wmax = -1;
  if (itermask) {
    int ifirst = __ffs(itermask) - 1;
    int ilast = 31 - __clz(itermask);
    dmin = (int)d0 + DSTEP * ifirst;
    dmax = (int)d0 + DSTEP * ilast;
    hmin = hmax = (int)h;
    wmin = wb + (__ffs(elemmask) - 1);
    wmax = wb + (31 - __clz(elemmask));
  }

  dmin = wred_min(dmin); dmax = wred_max(dmax);
  hmin = wred_min(hmin); hmax = wred_max(hmax);
  wmin = wred_min(wmin); wmax = wred_max(wmax);

  __shared__ int sred[4][6];
  __shared__ bool amLast;
  const int wave = threadIdx.x >> 6, lane = threadIdx.x & 63;
  if (lane == 0) {
    sred[wave][0] = dmin; sred[wave][1] = dmax;
    sred[wave][2] = hmin; sred[wave][3] = hmax;
    sred[wave][4] = wmin; sred[wave][5] = wmax;
  }
  __syncthreads();
  if (threadIdx.x == 0) {
    int Dm = min(min(sred[0][0], sred[1][0]), min(sred[2][0], sred[3][0]));
    int DM = max(max(sred[0][1], sred[1][1]), max(sred[2][1], sred[3][1]));
    int Hm = min(min(sred[0][2], sred[1][2]), min(sred[2][2], sred[3][2]));
    int HM = max(max(sred[0][3], sred[1][3]), max(sred[2][3], sred[3][3]));
    int Wm = min(min(sred[0][4], sred[1][4]), min(sred[2][4], sred[3][4]));
    int WM = max(max(sred[0][5], sred[1][5]), max(sred[2][5], sred[3][5]));
    if (DM >= 0) {
      atomicMax(&bneg[b * 3 + 0], (DSZ - 1) - Dm);   // min encoded as max
      atomicMax(&bneg[b * 3 + 1], (HSZ - 1) - Hm);
      atomicMax(&bneg[b * 3 + 2], (WSZ - 1) - Wm);
      atomicMax(&bmax[b * 3 + 0], DM);
      atomicMax(&bmax[b * 3 + 1], HM);
      atomicMax(&bmax[b * 3 + 2], WM);
    }
    // release our atomicMax writes; acquire everyone else's when we're last
    int old = __hip_atomic_fetch_add(cntA, 1, __ATOMIC_ACQ_REL,
                                     __HIP_MEMORY_SCOPE_AGENT);
    amLast = (old == TOTAL_BLOCKS - 1);
  }
  __syncthreads();

  if (amLast && threadIdx.x == 0) {
    // compute box params for all 4 batches (trivial scalar work)
#pragma unroll
    for (int bb = 0; bb < BATCH; ++bb) {
      int DM2 = bmax[bb * 3 + 0], HM2 = bmax[bb * 3 + 1], WM2 = bmax[bb * 3 + 2];
      int Dm2 = (DSZ - 1) - bneg[bb * 3 + 0];
      int Hm2 = (HSZ - 1) - bneg[bb * 3 + 1];
      int Wm2 = (WSZ - 1) - bneg[bb * 3 + 2];
      int o[6] = {0, 0, 0, 0, 0, 0};
      if (DM2 >= 0) {
        axis_box(Dm2, DM2, DSZ, &o[0], &o[1]);
        axis_box(Hm2, HM2, HSZ, &o[2], &o[3]);
        axis_box(Wm2, WM2, WSZ, &o[4], &o[5]);
      }
#pragma unroll
      for (int k = 0; k < 6; ++k) boxp[bb * 8 + k] = o[k];
    }
  }
}

// ---------------- loss: weighted SSE + last-block final ----------------
__global__ __launch_bounds__(NT) void ml_loss(const float* __restrict__ pred,
                                              const float* __restrict__ tru,
                                              const int* __restrict__ boxp,
                                              int* __restrict__ cntB,
                                              float* __restrict__ partials,
                                              float* __restrict__ out) {
  const int b = blockIdx.y;
  const int lod = boxp[b * 8 + 0], hid = boxp[b * 8 + 1];
  const int loh = boxp[b * 8 + 2], hih = boxp[b * 8 + 3];
  const int low = boxp[b * 8 + 4], hiw = boxp[b * 8 + 5];

  const vfloat4* p4 = reinterpret_cast<const vfloat4*>(pred + (size_t)b * SPATIAL);
  const vfloat4* t4 = reinterpret_cast<const vfloat4*>(tru + (size_t)b * SPATIAL);

  const unsigned q0 = blockIdx.x * NT + threadIdx.x;   // < 256000
  const unsigned d0 = q0 / 6400u;
  const unsigned rem = q0 - d0 * 6400u;                // loop-invariant
  const unsigned h = rem / 40u;
  const int wb = (int)(rem - h * 40u) * 4;

  const bool inh = ((int)h >= loh) & ((int)h < hih);
  const float wx = (inh & (wb + 0 >= low) & (wb + 0 < hiw)) ? 1.0f : 0.1f;
  const float wy = (inh & (wb + 1 >= low) & (wb + 1 < hiw)) ? 1.0f : 0.1f;
  const float wz = (inh & (wb + 2 >= low) & (wb + 2 < hiw)) ? 1.0f : 0.1f;
  const float ww = (inh & (wb + 3 >= low) & (wb + 3 < hiw)) ? 1.0f : 0.1f;

  // stage ALL 8 loads first: force 8 loads in flight per thread
  vfloat4 pv[ITERS], tv[ITERS];
#pragma unroll
  for (int i = 0; i < ITERS; ++i) {
    pv[i] = p4[q0 + (size_t)i * STRIDE_Q];
    tv[i] = t4[q0 + (size_t)i * STRIDE_Q];
  }

  float s0 = 0.0f, s1 = 0.0f, s2 = 0.0f, s3 = 0.0f;
#pragma unroll
  for (int i = 0; i < ITERS; ++i) {
    int d = (int)d0 + DSTEP * i;
    bool ind = (d >= lod) & (d < hid);
    float rx = ind ? wx : 0.1f;
    float ry = ind ? wy : 0.1f;
    float rz = ind ? wz : 0.1f;
    float rw = ind ? ww : 0.1f;
    float a;
    a = rx * pv[i][0] - rx * tv[i][0]; s0 = fmaf(a, a, s0);
    a = ry * pv[i][1] - ry * tv[i][1]; s1 = fmaf(a, a, s1);
    a = rz * pv[i][2] - rz * tv[i][2]; s2 = fmaf(a, a, s2);
    a = rw * pv[i][3] - rw * tv[i][3]; s3 = fmaf(a, a, s3);
  }
  float s = (s0 + s1) + (s2 + s3);

#pragma unroll
  for (int o = 32; o; o >>= 1) s += __shfl_xor(s, o);
  __shared__ float ls[4];
  __shared__ bool amLast;
  const int wave = threadIdx.x >> 6, lane = threadIdx.x & 63;
  if (lane == 0) ls[wave] = s;
  __syncthreads();
  if (threadIdx.x == 0) {
    partials[(size_t)b * PB + blockIdx.x] = ls[0] + ls[1] + ls[2] + ls[3];
    int old = __hip_atomic_fetch_add(cntB, 1, __ATOMIC_ACQ_REL,
                                     __HIP_MEMORY_SCOPE_AGENT);
    amLast = (old == TOTAL_BLOCKS - 1);
  }
  __syncthreads();

  if (amLast) {
    double acc = 0.0;
    for (int i = threadIdx.x; i < NPART; i += NT) acc += (double)partials[i];
#pragma unroll
    for (int o = 32; o; o >>= 1) acc += __shfl_xor(acc, o);
    __shared__ double ld[4];
    if (lane == 0) ld[wave] = acc;
    __syncthreads();
    if (threadIdx.x == 0)
      out[0] = (float)((ld[0] + ld[1] + ld[2] + ld[3]) / (double)((size_t)BATCH * SPATIAL));
  }
}

extern "C" void kernel_launch(void* const* d_in, const int* in_sizes, int n_in,
                              void* d_out, int out_size, void* d_ws, size_t ws_size,
                              hipStream_t stream) {
  const float* y_pred = (const float*)d_in[0];
  const float* y_true = (const float*)d_in[1];
  const int*   mask   = (const int*)d_in[2];
  float* out = (float*)d_out;

  char* ws = (char*)d_ws;
  int*   bneg     = (int*)(ws + WS_NEG);
  int*   bmax     = (int*)(ws + WS_MAX);
  int*   cntA     = (int*)(ws + WS_CNTA);
  int*   cntB     = (int*)(ws + WS_CNTB);
  int*   boxp     = (int*)(ws + WS_BOXP);
  float* partials = (float*)(ws + WS_PART);

  ml_init<<<1, 64, 0, stream>>>((int*)ws);
  ml_bbox<<<dim3(PB, BATCH), NT, 0, stream>>>(mask, bneg, bmax, cntA, boxp);
  ml_loss<<<dim3(PB, BATCH), NT, 0, stream>>>(y_pred, y_true, boxp, cntB,
                                              partials, out);
}